// Round 3
// baseline (844.097 us; speedup 1.0000x reference)
//
#include <hip/hip_runtime.h>
#include <stdint.h>

typedef _Float16 f16;
typedef _Float16 f16x8 __attribute__((ext_vector_type(8)));
typedef _Float16 f16x4 __attribute__((ext_vector_type(4)));
typedef float f32x4 __attribute__((ext_vector_type(4)));

#define S_TOK 8192
#define DDIM  512
#define L2E   1.44269504088896340736f
#define QSCALE 0.04419417382415922f   // 1/sqrt(512)
#define NSLOT 320
#define GTOT  8320                    // total KVB=32 iterations over all 64 tiles

__device__ __forceinline__ void gload_lds16(const void* g, void* l) {
  __builtin_amdgcn_global_load_lds((const __attribute__((address_space(1))) void*)g,
                                   (__attribute__((address_space(3))) void*)l, 16, 0, 0);
}

// ---------------- init slot-tile table -----------------------------------
__global__ void k_init(int* tp) {
  int i = blockIdx.x * 64 + threadIdx.x;
  if (i < NSLOT) tp[i] = -1;
}

// ---------------- convert f32 -> f16 --------------------------------------
__global__ __launch_bounds__(256) void k_convert(
    const float* __restrict__ X, const float* __restrict__ Wq,
    const float* __restrict__ Wk, const float* __restrict__ Wv,
    f16* __restrict__ Xh, f16* __restrict__ Wh) {
  const int SD = S_TOK * DDIM;
  const int DD = DDIM * DDIM;
  int i4 = (blockIdx.x * 256 + threadIdx.x) * 4;
  if (i4 < SD) {
    f32x4 v = *(const f32x4*)(X + i4);
    f16x4 h = {(f16)v[0], (f16)v[1], (f16)v[2], (f16)v[3]};
    *(f16x4*)(Xh + i4) = h;
  } else {
    int j = i4 - SD;
    int mat = j >> 18;
    const float* src = (mat == 0) ? Wq : (mat == 1 ? Wk : Wv);
    f32x4 v = *(const f32x4*)(src + (j & (DD - 1)));
    f16x4 h = {(f16)v[0], (f16)v[1], (f16)v[2], (f16)v[3]};
    *(f16x4*)(Wh + j) = h;
  }
}

// ---------------- QKV projection ------------------------------------------
// Q,K row-major (Q pre-scaled). V in packed MFMA-B-frag order:
// frag(K=s/32, f=d/16) at byte (K*32+f)*1024 + lane*16 + j*2, holding
// V[K*32 + (lane>>4)*8 + j][f*16 + (lane&15)]
__global__ __launch_bounds__(256) void k_proj(
    const f16* __restrict__ Xh, const f16* __restrict__ Wh,
    f16* __restrict__ Qh, f16* __restrict__ Kh, f16* __restrict__ VB) {
  __shared__ __align__(16) char Al[128 * 128];
  __shared__ __align__(16) char Bl[128 * 128];
  const int tid = threadIdx.x;
  const int w = tid >> 6, lane = tid & 63;
  const int m0 = blockIdx.x * 128;
  const int n0 = blockIdx.y * 128;
  const int wr = (w >> 1) * 64;
  const int wc = (w & 1) * 64;

  f32x4 acc[4][4];
#pragma unroll
  for (int i = 0; i < 4; ++i)
#pragma unroll
    for (int j = 0; j < 4; ++j) acc[i][j] = (f32x4){0.f, 0.f, 0.f, 0.f};

  const char* Xb = (const char*)Xh;
  const char* Wb = (const char*)Wh;

  for (int kb = 0; kb < DDIM; kb += 64) {
    __syncthreads();
#pragma unroll
    for (int i = 0; i < 4; ++i) {
      int ch = w * 4 + i;
      int srow = lane >> 3;
      int scol = ((lane & 7) * 16) ^ (srow << 4);
      gload_lds16(Xb + (size_t)(m0 + ch * 8 + srow) * 1024 + kb * 2 + scol, Al + ch * 1024);
      gload_lds16(Wb + (size_t)(n0 + ch * 8 + srow) * 1024 + kb * 2 + scol, Bl + ch * 1024);
    }
    __syncthreads();
#pragma unroll
    for (int ks = 0; ks < 2; ++ks) {
      f16x8 a[4], b[4];
#pragma unroll
      for (int mf = 0; mf < 4; ++mf) {
        int row = wr + mf * 16 + (lane & 15);
        int col = (ks * 64 + ((lane >> 4) * 16)) ^ ((row & 7) << 4);
        a[mf] = *(const f16x8*)(Al + row * 128 + col);
      }
#pragma unroll
      for (int nf = 0; nf < 4; ++nf) {
        int row = wc + nf * 16 + (lane & 15);
        int col = (ks * 64 + ((lane >> 4) * 16)) ^ ((row & 7) << 4);
        b[nf] = *(const f16x8*)(Bl + row * 128 + col);
      }
#pragma unroll
      for (int mf = 0; mf < 4; ++mf)
#pragma unroll
        for (int nf = 0; nf < 4; ++nf)
          acc[mf][nf] = __builtin_amdgcn_mfma_f32_16x16x32_f16(a[mf], b[nf], acc[mf][nf], 0, 0, 0);
    }
  }
  int mat = n0 >> 9;
  int nbase = n0 & 511;
  if (mat == 2) {
#pragma unroll
    for (int mf = 0; mf < 4; ++mf) {
      int R0 = m0 + wr + mf * 16 + (lane >> 4) * 4;
      int K = R0 >> 5;
      int lhi = ((R0 >> 3) & 3) * 16;
      int j0 = R0 & 7;
#pragma unroll
      for (int nf = 0; nf < 4; ++nf) {
        int col = nbase + wc + nf * 16 + (lane & 15);
        f16x4 h = {(f16)acc[mf][nf][0], (f16)acc[mf][nf][1],
                   (f16)acc[mf][nf][2], (f16)acc[mf][nf][3]};
        *(f16x4*)((char*)VB + (size_t)(K * 32 + (col >> 4)) * 1024 +
                  (lhi + (col & 15)) * 16 + j0 * 2) = h;
      }
    }
  } else {
    f16* dst = (mat == 0) ? Qh : Kh;
    float scale = (mat == 0) ? QSCALE : 1.0f;
#pragma unroll
    for (int mf = 0; mf < 4; ++mf)
#pragma unroll
      for (int nf = 0; nf < 4; ++nf)
#pragma unroll
        for (int r = 0; r < 4; ++r) {
          int row = m0 + wr + mf * 16 + (lane >> 4) * 4 + r;
          int col = nbase + wc + nf * 16 + (lane & 15);
          dst[(size_t)row * DDIM + col] = (f16)(acc[mf][nf][r] * scale);
        }
  }
}

// ---------------- causal flash attention, v3 -------------------------------
// BM=128, KVB=32, 256 blocks x 8 waves. Per iter: softmax[it] phase, then a
// fused MFMA phase interleaving PV[it] (all 128 rows x 64-d slice per wave,
// P from LDS, V direct-from-global regs) with QK^T[it+1] (K from LDS dbuf).
__global__ __launch_bounds__(512, 2) void k_flash(
    const f16* __restrict__ Qh, const f16* __restrict__ Kh,
    const f16* __restrict__ VBg, f16* __restrict__ Opart,
    float* __restrict__ Mpart, float* __restrict__ Lpart,
    int* __restrict__ TilePart) {
  __shared__ __align__(16) char Kl[2][32768];   // K tile [32][512 f16] swizzled
  __shared__ __align__(16) char Pl[8192];       // P [128][32] f16, bits4-5 ^= (row>>1)&3
  __shared__ __align__(16) float Al[128];       // per-row rescale alpha
  __shared__ __align__(16) float Ll[128];       // per-row l (epilogue)
  __shared__ __align__(16) int Fl[8];           // per-wave rescale flags

  const int tid = threadIdx.x;
  const int w = tid >> 6, lane = tid & 63;
  const int l15 = lane & 15, l4 = lane >> 4;

  int bid = blockIdx.x;
  int b = (bid & 7) * 32 + (bid >> 3);          // XCD-contiguous logical id
  int g  = (GTOT * b) >> 8;
  int g1 = (GTOT * (b + 1)) >> 8;
  int t = 0;
  while (2 * (t + 1) * (t + 2) <= g) ++t;

  const char* Kb = (const char*)Kh;
  const char* Vb = (const char*)VBg;

#define STAGEK(KB, BUF) do {                                                   \
    _Pragma("unroll")                                                          \
    for (int i_ = 0; i_ < 4; ++i_) {                                           \
      int row_ = w * 4 + i_;                                                   \
      int scol_ = (lane * 16) ^ ((row_ & 7) << 4);                             \
      gload_lds16(Kb + (size_t)((KB) + row_) * 1024 + scol_, (BUF) + row_ * 1024); \
    } } while (0)

#define LOADV(KB) do {                                                         \
    const char* vs_ = Vb + (size_t)((KB) >> 5) * 32768 + (size_t)w * 4096;     \
    _Pragma("unroll")                                                          \
    for (int nf_ = 0; nf_ < 4; ++nf_)                                          \
      vreg[nf_] = *(const f16x8*)(vs_ + nf_ * 1024 + lane * 16); } while (0)

#define QKT(BUF, S0, S1) do {                                                  \
    S0 = (f32x4){0.f, 0.f, 0.f, 0.f}; S1 = (f32x4){0.f, 0.f, 0.f, 0.f};        \
    _Pragma("unroll")                                                          \
    for (int ks_ = 0; ks_ < 16; ++ks_) {                                       \
      int off_ = ks_ * 64 + l4 * 16;                                           \
      f16x8 kf0_ = *(const f16x8*)((BUF) + l15 * 1024 + (off_ ^ ((l15 & 7) << 4))); \
      S0 = __builtin_amdgcn_mfma_f32_16x16x32_f16(qf[ks_], kf0_, S0, 0, 0, 0); \
      f16x8 kf1_ = *(const f16x8*)((BUF) + (16 + l15) * 1024 + (off_ ^ ((l15 & 7) << 4))); \
      S1 = __builtin_amdgcn_mfma_f32_16x16x32_f16(qf[ks_], kf1_, S1, 0, 0, 0); \
    } } while (0)

  while (g < g1) {
    int Ct  = 2 * t * (t + 1);
    int Ct1 = 2 * (t + 1) * (t + 2);
    int gend = min(g1, Ct1);
    int n = gend - g;
    int kb0 = (g - Ct) * 32;
    int q0 = t * 128;
    int slot = b + t;

    // Q fragments: rows q0 + w*16 + l15, full D
    f16x8 qf[16];
    {
      const f16* qp = Qh + (size_t)(q0 + w * 16 + l15) * DDIM + l4 * 8;
#pragma unroll
      for (int ks = 0; ks < 16; ++ks) qf[ks] = *(const f16x8*)(qp + ks * 32);
    }
    f32x4 acc[32];
#pragma unroll
    for (int i = 0; i < 32; ++i) acc[i] = (f32x4){0.f, 0.f, 0.f, 0.f};
    float mreg[4], lreg[4];
#pragma unroll
    for (int r = 0; r < 4; ++r) { mreg[r] = -3.0e38f; lreg[r] = 0.f; }
    f16x8 vreg[4];
    f32x4 s0, s1;

    // prologue: K[0], V[0], K[1]
    STAGEK(kb0, Kl[0]);
    LOADV(kb0);
    if (n > 1) STAGEK(kb0 + 32, Kl[1]);
    asm volatile("s_waitcnt vmcnt(0)" ::: "memory");
    __builtin_amdgcn_s_barrier();
    QKT(Kl[0], s0, s1);

    for (int it = 0; it < n; ++it) {
      // ---- phase A: softmax[it] (s0/s1 -> P, Al, Fl, mreg, lreg)
      {
        int kb = kb0 + it * 32;
        float p0[4], p1[4], mx[4], alpha[4];
        int qrb = q0 + w * 16 + l4 * 4;
        int kc = kb + l15;
#pragma unroll
        for (int r = 0; r < 4; ++r) {
          int qr = qrb + r;
          float x0 = (kc      <= qr) ? s0[r] : -3.0e38f;
          float x1 = (kc + 16 <= qr) ? s1[r] : -3.0e38f;
          p0[r] = x0; p1[r] = x1;
          float m = fmaxf(x0, x1);
          m = fmaxf(m, __shfl_xor(m, 1, 64));
          m = fmaxf(m, __shfl_xor(m, 2, 64));
          m = fmaxf(m, __shfl_xor(m, 4, 64));
          m = fmaxf(m, __shfl_xor(m, 8, 64));
          mx[r] = m;
        }
        bool need = (mx[0] > mreg[0] + 8.f) || (mx[1] > mreg[1] + 8.f) ||
                    (mx[2] > mreg[2] + 8.f) || (mx[3] > mreg[3] + 8.f);
        need = __any(need);
        if (need) {
#pragma unroll
          for (int r = 0; r < 4; ++r) {
            float mn = fmaxf(mreg[r], mx[r]);
            float al = exp2f((mreg[r] - mn) * L2E);
            lreg[r] *= al;
            mreg[r] = mn;
            alpha[r] = al;
          }
        } else {
#pragma unroll
          for (int r = 0; r < 4; ++r) alpha[r] = 1.0f;
        }
        if (l15 == 0) {
#pragma unroll
          for (int r = 0; r < 4; ++r) Al[w * 16 + l4 * 4 + r] = alpha[r];
        }
        if (lane == 0) Fl[w] = need ? 1 : 0;
#pragma unroll
        for (int r = 0; r < 4; ++r) {
          int qr = qrb + r;
          float e0 = (kc      <= qr) ? exp2f((p0[r] - mreg[r]) * L2E) : 0.f;
          float e1 = (kc + 16 <= qr) ? exp2f((p1[r] - mreg[r]) * L2E) : 0.f;
          p0[r] = e0; p1[r] = e1;
          float ss = e0 + e1;
          ss += __shfl_xor(ss, 1, 64);
          ss += __shfl_xor(ss, 2, 64);
          ss += __shfl_xor(ss, 4, 64);
          ss += __shfl_xor(ss, 8, 64);
          lreg[r] += ss;
        }
        // P writes: byte = row*64 + ((col*2) ^ (((row>>1)&3)<<4))
#pragma unroll
        for (int r = 0; r < 4; ++r) {
          int row = w * 16 + l4 * 4 + r;
          int sw = ((row >> 1) & 3) << 4;
          *(f16*)(Pl + row * 64 + ((l15 * 2) ^ sw))        = (f16)p0[r];
          *(f16*)(Pl + row * 64 + (((16 + l15) * 2) ^ sw)) = (f16)p1[r];
        }
      }
      asm volatile("s_waitcnt vmcnt(0) lgkmcnt(0)" ::: "memory");
      __builtin_amdgcn_s_barrier();

      // ---- fused phase: rescale, PV[it] (+ QK^T[it+1])
      {
        int fl0 = Fl[0] | Fl[1] | Fl[2] | Fl[3];
        int fl1 = Fl[4] | Fl[5] | Fl[6] | Fl[7];
        if (fl0 | fl1) {
#pragma unroll
          for (int rf = 0; rf < 8; ++rf) {
            f32x4 av = *(const f32x4*)(Al + rf * 16 + l4 * 4);
#pragma unroll
            for (int nf = 0; nf < 4; ++nf) {
              acc[rf * 4 + nf][0] *= av[0];
              acc[rf * 4 + nf][1] *= av[1];
              acc[rf * 4 + nf][2] *= av[2];
              acc[rf * 4 + nf][3] *= av[3];
            }
          }
        }
        if (it + 2 < n) STAGEK(kb0 + (it + 2) * 32, Kl[it & 1]);

        int psw = ((l15 >> 1) & 3) << 4;
        if (it + 1 < n) {
          const char* KlN = Kl[(it + 1) & 1];
          f32x4 ns0 = (f32x4){0.f, 0.f, 0.f, 0.f};
          f32x4 ns1 = (f32x4){0.f, 0.f, 0.f, 0.f};
          f16x8 pa;
#pragma unroll
          for (int ks = 0; ks < 16; ++ks) {
            int off = ks * 64 + l4 * 16;
            f16x8 kf0 = *(const f16x8*)(KlN + l15 * 1024 + (off ^ ((l15 & 7) << 4)));
            ns0 = __builtin_amdgcn_mfma_f32_16x16x32_f16(qf[ks], kf0, ns0, 0, 0, 0);
            if ((ks & 1) == 0) {
              int rf = ks >> 1;
              pa = *(const f16x8*)(Pl + (rf * 16 + l15) * 64 + ((l4 * 16) ^ psw));
            }
            int p = ks * 2;
            acc[p]   = __builtin_amdgcn_mfma_f32_16x16x32_f16(pa, vreg[p & 3], acc[p], 0, 0, 0);
            f16x8 kf1 = *(const f16x8*)(KlN + (16 + l15) * 1024 + (off ^ ((l15 & 7) << 4)));
            ns1 = __builtin_amdgcn_mfma_f32_16x16x32_f16(qf[ks], kf1, ns1, 0, 0, 0);
            acc[p + 1] = __builtin_amdgcn_mfma_f32_16x16x32_f16(pa, vreg[(p + 1) & 3], acc[p + 1], 0, 0, 0);
          }
          s0 = ns0; s1 = ns1;
          LOADV(kb0 + (it + 1) * 32);
        } else {
          f16x8 pa;
#pragma unroll
          for (int ks = 0; ks < 16; ++ks) {
            if ((ks & 1) == 0) {
              int rf = ks >> 1;
              pa = *(const f16x8*)(Pl + (rf * 16 + l15) * 64 + ((l4 * 16) ^ psw));
            }
            int p = ks * 2;
            acc[p]     = __builtin_amdgcn_mfma_f32_16x16x32_f16(pa, vreg[p & 3], acc[p], 0, 0, 0);
            acc[p + 1] = __builtin_amdgcn_mfma_f32_16x16x32_f16(pa, vreg[(p + 1) & 3], acc[p + 1], 0, 0, 0);
          }
        }
      }
      __builtin_amdgcn_s_barrier();
    }

    // ---- epilogue: broadcast l, write partial
    if (l15 == 0) {
#pragma unroll
      for (int r = 0; r < 4; ++r) Ll[w * 16 + l4 * 4 + r] = lreg[r];
    }
    asm volatile("s_waitcnt lgkmcnt(0)" ::: "memory");
    __builtin_amdgcn_s_barrier();
    {
      f16* op = Opart + (size_t)slot * (128 * 512);
#pragma unroll
      for (int rf = 0; rf < 8; ++rf) {
        f32x4 lv = *(const f32x4*)(Ll + rf * 16 + l4 * 4);
        f32x4 inv;
#pragma unroll
        for (int r = 0; r < 4; ++r) inv[r] = (lv[r] > 0.f) ? 1.f / lv[r] : 0.f;
#pragma unroll
        for (int nf = 0; nf < 4; ++nf) {
          int col = w * 64 + nf * 16 + l15;
#pragma unroll
          for (int r = 0; r < 4; ++r) {
            int row = rf * 16 + l4 * 4 + r;
            op[(size_t)row * 512 + col] = (f16)(acc[rf * 4 + nf][r] * inv[r]);
          }
        }
      }
      if (l15 == 0) {
#pragma unroll
        for (int r = 0; r < 4; ++r) {
          int row = w * 16 + l4 * 4 + r;
          Mpart[slot * 128 + row] = mreg[r];
          Lpart[slot * 128 + row] = lreg[r];
        }
      }
      if (tid == 0) TilePart[slot] = t;
    }
    __builtin_amdgcn_s_barrier();
    g = gend;
    ++t;
  }
#undef STAGEK
#undef LOADV
#undef QKT
}

// ---------------- combine partials -> out --------------------------------
__global__ __launch_bounds__(256) void k_reduce(
    const f16* __restrict__ Opart, const float* __restrict__ Mpart,
    const float* __restrict__ Lpart, const int* __restrict__ TilePart,
    float* __restrict__ out) {
  __shared__ int tp[NSLOT];
  __shared__ int sl[16];
  __shared__ int scnt;
  int tid = threadIdx.x;
  int t = blockIdx.x >> 2, rg = blockIdx.x & 3;
  for (int s = tid; s < NSLOT; s += 256) tp[s] = TilePart[s];
  __syncthreads();
  if (tid == 0) {
    int c = 0;
    for (int s = 0; s < NSLOT; ++s)
      if (tp[s] == t && c < 16) sl[c++] = s;
    scnt = c;
  }
  __syncthreads();
  int cnt = scnt;
  int rowIn = rg * 32 + (tid >> 3);
  int row = t * 128 + rowIn;
  int col0 = (tid & 7) * 64;

  float M = -3.0e38f;
  for (int i = 0; i < cnt; ++i) M = fmaxf(M, Mpart[sl[i] * 128 + rowIn]);
  float a[64];
#pragma unroll
  for (int j = 0; j < 64; ++j) a[j] = 0.f;
  float denom = 0.f;
  for (int i = 0; i < cnt; ++i) {
    int s = sl[i];
    float m = Mpart[s * 128 + rowIn];
    float l = Lpart[s * 128 + rowIn];
    float wgt = exp2f((m - M) * L2E) * l;
    denom += wgt;
    const f16* op = Opart + (size_t)s * 65536 + rowIn * 512 + col0;
#pragma unroll
    for (int v = 0; v < 8; ++v) {
      f16x8 x = *(const f16x8*)(op + v * 8);
#pragma unroll
      for (int j = 0; j < 8; ++j) a[v * 8 + j] += wgt * (float)x[j];
    }
  }
  float inv = (denom > 0.f) ? 1.f / denom : 0.f;
  float* o = out + (size_t)row * 512 + col0;
#pragma unroll
  for (int j = 0; j < 64; ++j) o[j] = a[j] * inv;
}

extern "C" void kernel_launch(void* const* d_in, const int* in_sizes, int n_in,
                              void* d_out, int out_size, void* d_ws, size_t ws_size,
                              hipStream_t stream) {
  const float* X  = (const float*)d_in[0];
  const float* Wq = (const float*)d_in[2];
  const float* Wk = (const float*)d_in[3];
  const float* Wv = (const float*)d_in[4];
  float* out = (float*)d_out;

  char* ws = (char*)d_ws;
  f16*   Opart = (f16*)(ws);                               // 40 MiB
  float* Mpart = (float*)(ws + (40u << 20));               // 160 KiB
  float* Lpart = (float*)(ws + (41u << 20));               // 160 KiB
  int*   TileP = (int*)(ws + (42u << 20));                 // 1.25 KiB
  f16* Qh = (f16*)(ws + (43u << 20));                      // 8 MiB (pre-scaled)
  f16* Kh = (f16*)(ws + (51u << 20));                      // 8 MiB
  f16* VB = (f16*)(ws + (59u << 20));                      // 8 MiB packed frags
  f16* Xh = (f16*)(ws + (67u << 20));                      // 8 MiB
  f16* Wh = (f16*)(ws + (75u << 20));                      // 1.5 MiB

  k_init<<<5, 64, 0, stream>>>(TileP);
  k_convert<<<4864, 256, 0, stream>>>(X, Wq, Wk, Wv, Xh, Wh);
  dim3 gp(64, 12);
  k_proj<<<gp, 256, 0, stream>>>(Xh, Wh, Qh, Kh, VB);
  k_flash<<<256, 512, 0, stream>>>(Qh, Kh, VB, Opart, Mpart, Lpart, TileP);
  k_reduce<<<256, 256, 0, stream>>>(Opart, Mpart, Lpart, TileP, out);
}

// Round 4
// 389.395 us; speedup vs baseline: 2.1677x; 2.1677x over previous
//
#include <hip/hip_runtime.h>
#include <stdint.h>

typedef _Float16 f16;
typedef _Float16 f16x8 __attribute__((ext_vector_type(8)));
typedef _Float16 f16x4 __attribute__((ext_vector_type(4)));
typedef float f32x4 __attribute__((ext_vector_type(4)));

#define S_TOK 8192
#define DDIM  512
#define L2E   1.44269504088896340736f
#define QSCALE 0.04419417382415922f   // 1/sqrt(512)
#define NSLOT 320
#define GTOT  8320                    // total KVB=32 iterations over all 64 tiles

__device__ __forceinline__ void gload_lds16(const void* g, void* l) {
  __builtin_amdgcn_global_load_lds((const __attribute__((address_space(1))) void*)g,
                                   (__attribute__((address_space(3))) void*)l, 16, 0, 0);
}

// DPP 16-lane (row) reductions — pure VALU, no LDS pipe.
template <int C>
__device__ __forceinline__ float fdpp(float x) {
  return __builtin_bit_cast(float,
      __builtin_amdgcn_update_dpp(0, __builtin_bit_cast(int, x), C, 0xF, 0xF, true));
}
__device__ __forceinline__ float rowmax16(float x) {
  x = fmaxf(x, fdpp<0xB1>(x));    // quad_perm [1,0,3,2]  (xor1)
  x = fmaxf(x, fdpp<0x4E>(x));    // quad_perm [2,3,0,1]  (xor2)
  x = fmaxf(x, fdpp<0x141>(x));   // row_half_mirror      (xor7)
  x = fmaxf(x, fdpp<0x140>(x));   // row_mirror           (xor15)
  return x;
}
__device__ __forceinline__ float rowsum16(float x) {
  x += fdpp<0xB1>(x);
  x += fdpp<0x4E>(x);
  x += fdpp<0x141>(x);
  x += fdpp<0x140>(x);
  return x;
}

// ---------------- init slot-tile table -----------------------------------
__global__ void k_init(int* tp) {
  int i = blockIdx.x * 64 + threadIdx.x;
  if (i < NSLOT) tp[i] = -1;
}

// ---------------- convert f32 -> f16 --------------------------------------
__global__ __launch_bounds__(256) void k_convert(
    const float* __restrict__ X, const float* __restrict__ Wq,
    const float* __restrict__ Wk, const float* __restrict__ Wv,
    f16* __restrict__ Xh, f16* __restrict__ Wh) {
  const int SD = S_TOK * DDIM;
  const int DD = DDIM * DDIM;
  int i4 = (blockIdx.x * 256 + threadIdx.x) * 4;
  if (i4 < SD) {
    f32x4 v = *(const f32x4*)(X + i4);
    f16x4 h = {(f16)v[0], (f16)v[1], (f16)v[2], (f16)v[3]};
    *(f16x4*)(Xh + i4) = h;
  } else {
    int j = i4 - SD;
    int mat = j >> 18;
    const float* src = (mat == 0) ? Wq : (mat == 1 ? Wk : Wv);
    f32x4 v = *(const f32x4*)(src + (j & (DD - 1)));
    f16x4 h = {(f16)v[0], (f16)v[1], (f16)v[2], (f16)v[3]};
    *(f16x4*)(Wh + j) = h;
  }
}

// ---------------- QKV projection ------------------------------------------
// Q,K row-major (Q pre-scaled). V in packed MFMA-B-frag order:
// frag(K=s/32, f=d/16) at byte (K*32+f)*1024 + lane*16 + j*2, holding
// V[K*32 + (lane>>4)*8 + j][f*16 + (lane&15)]
__global__ __launch_bounds__(256) void k_proj(
    const f16* __restrict__ Xh, const f16* __restrict__ Wh,
    f16* __restrict__ Qh, f16* __restrict__ Kh, f16* __restrict__ VB) {
  __shared__ __align__(16) char Al[128 * 128];
  __shared__ __align__(16) char Bl[128 * 128];
  const int tid = threadIdx.x;
  const int w = tid >> 6, lane = tid & 63;
  const int m0 = blockIdx.x * 128;
  const int n0 = blockIdx.y * 128;
  const int wr = (w >> 1) * 64;
  const int wc = (w & 1) * 64;

  f32x4 acc[4][4];
#pragma unroll
  for (int i = 0; i < 4; ++i)
#pragma unroll
    for (int j = 0; j < 4; ++j) acc[i][j] = (f32x4){0.f, 0.f, 0.f, 0.f};

  const char* Xb = (const char*)Xh;
  const char* Wb = (const char*)Wh;

  for (int kb = 0; kb < DDIM; kb += 64) {
    __syncthreads();
#pragma unroll
    for (int i = 0; i < 4; ++i) {
      int ch = w * 4 + i;
      int srow = lane >> 3;
      int scol = ((lane & 7) * 16) ^ (srow << 4);
      gload_lds16(Xb + (size_t)(m0 + ch * 8 + srow) * 1024 + kb * 2 + scol, Al + ch * 1024);
      gload_lds16(Wb + (size_t)(n0 + ch * 8 + srow) * 1024 + kb * 2 + scol, Bl + ch * 1024);
    }
    __syncthreads();
#pragma unroll
    for (int ks = 0; ks < 2; ++ks) {
      f16x8 a[4], b[4];
#pragma unroll
      for (int mf = 0; mf < 4; ++mf) {
        int row = wr + mf * 16 + (lane & 15);
        int col = (ks * 64 + ((lane >> 4) * 16)) ^ ((row & 7) << 4);
        a[mf] = *(const f16x8*)(Al + row * 128 + col);
      }
#pragma unroll
      for (int nf = 0; nf < 4; ++nf) {
        int row = wc + nf * 16 + (lane & 15);
        int col = (ks * 64 + ((lane >> 4) * 16)) ^ ((row & 7) << 4);
        b[nf] = *(const f16x8*)(Bl + row * 128 + col);
      }
#pragma unroll
      for (int mf = 0; mf < 4; ++mf)
#pragma unroll
        for (int nf = 0; nf < 4; ++nf)
          acc[mf][nf] = __builtin_amdgcn_mfma_f32_16x16x32_f16(a[mf], b[nf], acc[mf][nf], 0, 0, 0);
    }
  }
  int mat = n0 >> 9;
  int nbase = n0 & 511;
  if (mat == 2) {
#pragma unroll
    for (int mf = 0; mf < 4; ++mf) {
      int R0 = m0 + wr + mf * 16 + (lane >> 4) * 4;
      int K = R0 >> 5;
      int lhi = ((R0 >> 3) & 3) * 16;
      int j0 = R0 & 7;
#pragma unroll
      for (int nf = 0; nf < 4; ++nf) {
        int col = nbase + wc + nf * 16 + (lane & 15);
        f16x4 h = {(f16)acc[mf][nf][0], (f16)acc[mf][nf][1],
                   (f16)acc[mf][nf][2], (f16)acc[mf][nf][3]};
        *(f16x4*)((char*)VB + (size_t)(K * 32 + (col >> 4)) * 1024 +
                  (lhi + (col & 15)) * 16 + j0 * 2) = h;
      }
    }
  } else {
    f16* dst = (mat == 0) ? Qh : Kh;
    float scale = (mat == 0) ? QSCALE : 1.0f;
#pragma unroll
    for (int mf = 0; mf < 4; ++mf)
#pragma unroll
      for (int nf = 0; nf < 4; ++nf)
#pragma unroll
        for (int r = 0; r < 4; ++r) {
          int row = m0 + wr + mf * 16 + (lane >> 4) * 4 + r;
          int col = nbase + wc + nf * 16 + (lane & 15);
          dst[(size_t)row * DDIM + col] = (f16)(acc[mf][nf][r] * scale);
        }
  }
}

// ---------------- causal flash attention, v4 -------------------------------
// BM=128, KVB=32, 256 blocks x 8 waves, split-KV as v2. Per iter (2 barriers):
//   b1 -> QK^T(it) [K from LDS dbuf] -> softmax (DPP reduces, in-reg) ->
//   P write (shared LDS, swizzled) -> b2 -> rescale + PV(it)
// PV d-split: wave owns all 128 rows x 64-d slice; V direct-from-global
// (packed B-frags, prefetched at iter top). No V LDS, no shfl LDS traffic.
__global__ __launch_bounds__(512, 2) void k_flash(
    const f16* __restrict__ Qh, const f16* __restrict__ Kh,
    const f16* __restrict__ VBg, f16* __restrict__ Opart,
    float* __restrict__ Mpart, float* __restrict__ Lpart,
    int* __restrict__ TilePart) {
  __shared__ __align__(16) char Kl[2][32768];   // K tile [32][512 f16] swizzled
  __shared__ __align__(16) char Pl[8192];       // P [128][32] f16, bits4-5 ^= (row>>1)&3
  __shared__ __align__(16) float Al[128];       // per-row rescale alpha
  __shared__ __align__(16) float Ll[128];       // per-row l (epilogue)
  __shared__ __align__(16) int Fl[8];           // per-wave rescale flags

  const int tid = threadIdx.x;
  const int w = tid >> 6, lane = tid & 63;
  const int l15 = lane & 15, l4 = lane >> 4;

  int bid = blockIdx.x;
  int b = (bid & 7) * 32 + (bid >> 3);          // XCD-contiguous logical id
  int g  = (GTOT * b) >> 8;
  int g1 = (GTOT * (b + 1)) >> 8;
  int t = 0;
  while (2 * (t + 1) * (t + 2) <= g) ++t;

  const char* Kb = (const char*)Kh;
  const char* Vb = (const char*)VBg;

#define STAGEK(KB, BUF) do {                                                   \
    _Pragma("unroll")                                                          \
    for (int i_ = 0; i_ < 4; ++i_) {                                           \
      int row_ = w * 4 + i_;                                                   \
      int scol_ = (lane * 16) ^ ((row_ & 7) << 4);                             \
      gload_lds16(Kb + (size_t)((KB) + row_) * 1024 + scol_, (BUF) + row_ * 1024); \
    } } while (0)

#define LOADV(KB) do {                                                         \
    const char* vs_ = Vb + (size_t)((KB) >> 5) * 32768 + (size_t)w * 4096;     \
    _Pragma("unroll")                                                          \
    for (int nf_ = 0; nf_ < 4; ++nf_)                                          \
      vreg[nf_] = *(const f16x8*)(vs_ + nf_ * 1024 + lane * 16); } while (0)

  while (g < g1) {
    int Ct  = 2 * t * (t + 1);
    int Ct1 = 2 * (t + 1) * (t + 2);
    int gend = min(g1, Ct1);
    int n = gend - g;
    int kb0 = (g - Ct) * 32;
    int q0 = t * 128;
    int slot = b + t;

    // Q fragments: rows q0 + w*16 + l15, full D
    f16x8 qf[16];
    {
      const f16* qp = Qh + (size_t)(q0 + w * 16 + l15) * DDIM + l4 * 8;
#pragma unroll
      for (int ks = 0; ks < 16; ++ks) qf[ks] = *(const f16x8*)(qp + ks * 32);
    }
    f32x4 acc[32];
#pragma unroll
    for (int i = 0; i < 32; ++i) acc[i] = (f32x4){0.f, 0.f, 0.f, 0.f};
    float mreg[4], lreg[4];
#pragma unroll
    for (int r = 0; r < 4; ++r) { mreg[r] = -3.0e38f; lreg[r] = 0.f; }
    f16x8 vreg[4];
    f32x4 s0, s1;

    STAGEK(kb0, Kl[0]);     // prologue: K(0)

    for (int it = 0; it < n; ++it) {
      int nxt = (it + 1 < n) ? it + 1 : it;     // tail: harmless re-stage
      STAGEK(kb0 + nxt * 32, Kl[(it + 1) & 1]); // 4 loads
      LOADV(kb0 + it * 32);                     // 4 reg loads (used in PV below)
      asm volatile("s_waitcnt vmcnt(8)" ::: "memory");   // K(it) landed
      __builtin_amdgcn_s_barrier();             // b1

      // ---- QK^T(it): S[16 x 32] per wave over d=512
      {
        const char* KlB = Kl[it & 1];
        s0 = (f32x4){0.f, 0.f, 0.f, 0.f};
        s1 = (f32x4){0.f, 0.f, 0.f, 0.f};
        __builtin_amdgcn_s_setprio(1);
#pragma unroll
        for (int ks = 0; ks < 16; ++ks) {
          int off = ks * 64 + l4 * 16;
          f16x8 kf0 = *(const f16x8*)(KlB + l15 * 1024 + (off ^ ((l15 & 7) << 4)));
          s0 = __builtin_amdgcn_mfma_f32_16x16x32_f16(qf[ks], kf0, s0, 0, 0, 0);
          f16x8 kf1 = *(const f16x8*)(KlB + (16 + l15) * 1024 + (off ^ ((l15 & 7) << 4)));
          s1 = __builtin_amdgcn_mfma_f32_16x16x32_f16(qf[ks], kf1, s1, 0, 0, 0);
        }
        __builtin_amdgcn_s_setprio(0);
      }

      // ---- softmax (in-reg, DPP row reductions)
      {
        int kb = kb0 + it * 32;
        float p0[4], p1[4], mx[4], alpha[4];
        int qrb = q0 + w * 16 + l4 * 4;
        int kc = kb + l15;
#pragma unroll
        for (int r = 0; r < 4; ++r) {
          int qr = qrb + r;
          float x0 = (kc      <= qr) ? s0[r] : -3.0e38f;
          float x1 = (kc + 16 <= qr) ? s1[r] : -3.0e38f;
          p0[r] = x0; p1[r] = x1;
          mx[r] = rowmax16(fmaxf(x0, x1));
        }
        bool need = (mx[0] > mreg[0] + 8.f) || (mx[1] > mreg[1] + 8.f) ||
                    (mx[2] > mreg[2] + 8.f) || (mx[3] > mreg[3] + 8.f);
        need = __any(need);
        if (need) {
#pragma unroll
          for (int r = 0; r < 4; ++r) {
            float mn = fmaxf(mreg[r], mx[r]);
            float al = exp2f((mreg[r] - mn) * L2E);
            lreg[r] *= al;
            mreg[r] = mn;
            alpha[r] = al;
          }
        } else {
#pragma unroll
          for (int r = 0; r < 4; ++r) alpha[r] = 1.0f;
        }
        if (l15 == 0) {
#pragma unroll
          for (int r = 0; r < 4; ++r) Al[w * 16 + l4 * 4 + r] = alpha[r];
        }
        if (lane == 0) Fl[w] = need ? 1 : 0;
#pragma unroll
        for (int r = 0; r < 4; ++r) {
          int qr = qrb + r;
          float e0 = (kc      <= qr) ? exp2f((p0[r] - mreg[r]) * L2E) : 0.f;
          float e1 = (kc + 16 <= qr) ? exp2f((p1[r] - mreg[r]) * L2E) : 0.f;
          p0[r] = e0; p1[r] = e1;
          lreg[r] += rowsum16(e0 + e1);
        }
        // P writes: byte = row*64 + ((k*2) ^ (((row>>1)&3)<<4))
#pragma unroll
        for (int r = 0; r < 4; ++r) {
          int row = w * 16 + l4 * 4 + r;
          int sw = ((row >> 1) & 3) << 4;
          *(f16*)(Pl + row * 64 + ((l15 * 2) ^ sw))        = (f16)p0[r];
          *(f16*)(Pl + row * 64 + (((16 + l15) * 2) ^ sw)) = (f16)p1[r];
        }
      }
      asm volatile("s_waitcnt vmcnt(4) lgkmcnt(0)" ::: "memory"); // V(it) + P visible
      __builtin_amdgcn_s_barrier();             // b2

      // ---- rescale (rare) + PV(it): acc[rf][nf] += P[rf] @ Vfrag[nf]
      {
        int fl = Fl[0] | Fl[1] | Fl[2] | Fl[3] | Fl[4] | Fl[5] | Fl[6] | Fl[7];
        if (fl) {
#pragma unroll
          for (int rf = 0; rf < 8; ++rf) {
            f32x4 av = *(const f32x4*)(Al + rf * 16 + l4 * 4);
#pragma unroll
            for (int nf = 0; nf < 4; ++nf) {
              acc[rf * 4 + nf][0] *= av[0];
              acc[rf * 4 + nf][1] *= av[1];
              acc[rf * 4 + nf][2] *= av[2];
              acc[rf * 4 + nf][3] *= av[3];
            }
          }
        }
        int psw = ((l15 >> 1) & 3) << 4;
        __builtin_amdgcn_s_setprio(1);
#pragma unroll
        for (int rf = 0; rf < 8; ++rf) {
          f16x8 pa = *(const f16x8*)(Pl + (rf * 16 + l15) * 64 + ((l4 * 16) ^ psw));
#pragma unroll
          for (int nf = 0; nf < 4; ++nf)
            acc[rf * 4 + nf] = __builtin_amdgcn_mfma_f32_16x16x32_f16(pa, vreg[nf], acc[rf * 4 + nf], 0, 0, 0);
        }
        __builtin_amdgcn_s_setprio(0);
      }
    }

    // ---- epilogue: broadcast l, write partial
    if (l15 == 0) {
#pragma unroll
      for (int r = 0; r < 4; ++r) Ll[w * 16 + l4 * 4 + r] = lreg[r];
    }
    asm volatile("s_waitcnt lgkmcnt(0)" ::: "memory");
    __builtin_amdgcn_s_barrier();
    {
      f16* op = Opart + (size_t)slot * (128 * 512);
#pragma unroll
      for (int rf = 0; rf < 8; ++rf) {
        f32x4 lv = *(const f32x4*)(Ll + rf * 16 + l4 * 4);
        f32x4 inv;
#pragma unroll
        for (int r = 0; r < 4; ++r) inv[r] = (lv[r] > 0.f) ? 1.f / lv[r] : 0.f;
#pragma unroll
        for (int nf = 0; nf < 4; ++nf) {
          int col = w * 64 + nf * 16 + l15;
#pragma unroll
          for (int r = 0; r < 4; ++r) {
            int row = rf * 16 + l4 * 4 + r;
            op[(size_t)row * 512 + col] = (f16)(acc[rf * 4 + nf][r] * inv[r]);
          }
        }
      }
      if (l15 == 0) {
#pragma unroll
        for (int r = 0; r < 4; ++r) {
          int row = w * 16 + l4 * 4 + r;
          Mpart[slot * 128 + row] = mreg[r];
          Lpart[slot * 128 + row] = lreg[r];
        }
      }
      if (tid == 0) TilePart[slot] = t;
    }
    asm volatile("s_waitcnt vmcnt(0)" ::: "memory");  // reset vmcnt discipline
    __builtin_amdgcn_s_barrier();
    g = gend;
    ++t;
  }
#undef STAGEK
#undef LOADV
}

// ---------------- combine partials -> out --------------------------------
__global__ __launch_bounds__(256) void k_reduce(
    const f16* __restrict__ Opart, const float* __restrict__ Mpart,
    const float* __restrict__ Lpart, const int* __restrict__ TilePart,
    float* __restrict__ out) {
  __shared__ int tp[NSLOT];
  __shared__ int sl[16];
  __shared__ int scnt;
  int tid = threadIdx.x;
  int t = blockIdx.x >> 2, rg = blockIdx.x & 3;
  for (int s = tid; s < NSLOT; s += 256) tp[s] = TilePart[s];
  __syncthreads();
  if (tid == 0) {
    int c = 0;
    for (int s = 0; s < NSLOT; ++s)
      if (tp[s] == t && c < 16) sl[c++] = s;
    scnt = c;
  }
  __syncthreads();
  int cnt = scnt;
  int rowIn = rg * 32 + (tid >> 3);
  int row = t * 128 + rowIn;
  int col0 = (tid & 7) * 64;

  float M = -3.0e38f;
  for (int i = 0; i < cnt; ++i) M = fmaxf(M, Mpart[sl[i] * 128 + rowIn]);
  float a[64];
#pragma unroll
  for (int j = 0; j < 64; ++j) a[j] = 0.f;
  float denom = 0.f;
  for (int i = 0; i < cnt; ++i) {
    int s = sl[i];
    float m = Mpart[s * 128 + rowIn];
    float l = Lpart[s * 128 + rowIn];
    float wgt = exp2f((m - M) * L2E) * l;
    denom += wgt;
    const f16* op = Opart + (size_t)s * 65536 + rowIn * 512 + col0;
#pragma unroll
    for (int v = 0; v < 8; ++v) {
      f16x8 x = *(const f16x8*)(op + v * 8);
#pragma unroll
      for (int j = 0; j < 8; ++j) a[v * 8 + j] += wgt * (float)x[j];
    }
  }
  float inv = (denom > 0.f) ? 1.f / denom : 0.f;
  float* o = out + (size_t)row * 512 + col0;
#pragma unroll
  for (int j = 0; j < 64; ++j) o[j] = a[j] * inv;
}

extern "C" void kernel_launch(void* const* d_in, const int* in_sizes, int n_in,
                              void* d_out, int out_size, void* d_ws, size_t ws_size,
                              hipStream_t stream) {
  const float* X  = (const float*)d_in[0];
  const float* Wq = (const float*)d_in[2];
  const float* Wk = (const float*)d_in[3];
  const float* Wv = (const float*)d_in[4];
  float* out = (float*)d_out;

  char* ws = (char*)d_ws;
  f16*   Opart = (f16*)(ws);                               // 40 MiB
  float* Mpart = (float*)(ws + (40u << 20));               // 160 KiB
  float* Lpart = (float*)(ws + (41u << 20));               // 160 KiB
  int*   TileP = (int*)(ws + (42u << 20));                 // 1.25 KiB
  f16* Qh = (f16*)(ws + (43u << 20));                      // 8 MiB (pre-scaled)
  f16* Kh = (f16*)(ws + (51u << 20));                      // 8 MiB
  f16* VB = (f16*)(ws + (59u << 20));                      // 8 MiB packed frags
  f16* Xh = (f16*)(ws + (67u << 20));                      // 8 MiB
  f16* Wh = (f16*)(ws + (75u << 20));                      // 1.5 MiB

  k_init<<<5, 64, 0, stream>>>(TileP);
  k_convert<<<4864, 256, 0, stream>>>(X, Wq, Wk, Wv, Xh, Wh);
  dim3 gp(64, 12);
  k_proj<<<gp, 256, 0, stream>>>(Xh, Wh, Qh, Kh, VB);
  k_flash<<<256, 512, 0, stream>>>(Qh, Kh, VB, Opart, Mpart, Lpart, TileP);
  k_reduce<<<256, 256, 0, stream>>>(Opart, Mpart, Lpart, TileP, out);
}

// Round 5
// 270.040 us; speedup vs baseline: 3.1258x; 1.4420x over previous
//
#include <hip/hip_runtime.h>
#include <stdint.h>

typedef _Float16 f16;
typedef _Float16 f16x8 __attribute__((ext_vector_type(8)));
typedef _Float16 f16x4 __attribute__((ext_vector_type(4)));
typedef float f32x4 __attribute__((ext_vector_type(4)));

#define S_TOK 8192
#define DDIM  512
#define L2E   1.44269504088896340736f
#define QSCALE 0.04419417382415922f   // 1/sqrt(512)
#define NSLOT 320
#define GTOT  8320                    // total KVB=32 iterations over all 64 tiles

__device__ __forceinline__ void gload_lds16(const void* g, void* l) {
  __builtin_amdgcn_global_load_lds((const __attribute__((address_space(1))) void*)g,
                                   (__attribute__((address_space(3))) void*)l, 16, 0, 0);
}

// DPP 16-lane (row) reductions — pure VALU, no LDS pipe.
template <int C>
__device__ __forceinline__ float fdpp(float x) {
  return __builtin_bit_cast(float,
      __builtin_amdgcn_update_dpp(0, __builtin_bit_cast(int, x), C, 0xF, 0xF, true));
}
__device__ __forceinline__ float rowmax16(float x) {
  x = fmaxf(x, fdpp<0xB1>(x));    // quad_perm [1,0,3,2]  (xor1)
  x = fmaxf(x, fdpp<0x4E>(x));    // quad_perm [2,3,0,1]  (xor2)
  x = fmaxf(x, fdpp<0x141>(x));   // row_half_mirror      (xor7)
  x = fmaxf(x, fdpp<0x140>(x));   // row_mirror           (xor15)
  return x;
}
__device__ __forceinline__ float rowsum16(float x) {
  x += fdpp<0xB1>(x);
  x += fdpp<0x4E>(x);
  x += fdpp<0x141>(x);
  x += fdpp<0x140>(x);
  return x;
}

// ---------------- init slot-tile table -----------------------------------
__global__ void k_init(int* tp) {
  int i = blockIdx.x * 64 + threadIdx.x;
  if (i < NSLOT) tp[i] = -1;
}

// ---------------- convert f32 -> f16 --------------------------------------
__global__ __launch_bounds__(256) void k_convert(
    const float* __restrict__ X, const float* __restrict__ Wq,
    const float* __restrict__ Wk, const float* __restrict__ Wv,
    f16* __restrict__ Xh, f16* __restrict__ Wh) {
  const int SD = S_TOK * DDIM;
  const int DD = DDIM * DDIM;
  int i4 = (blockIdx.x * 256 + threadIdx.x) * 4;
  if (i4 < SD) {
    f32x4 v = *(const f32x4*)(X + i4);
    f16x4 h = {(f16)v[0], (f16)v[1], (f16)v[2], (f16)v[3]};
    *(f16x4*)(Xh + i4) = h;
  } else {
    int j = i4 - SD;
    int mat = j >> 18;
    const float* src = (mat == 0) ? Wq : (mat == 1 ? Wk : Wv);
    f32x4 v = *(const f32x4*)(src + (j & (DD - 1)));
    f16x4 h = {(f16)v[0], (f16)v[1], (f16)v[2], (f16)v[3]};
    *(f16x4*)(Wh + j) = h;
  }
}

// ---------------- QKV projection ------------------------------------------
// Q,K row-major (Q pre-scaled). V in packed MFMA-B-frag order:
// frag(K=s/32, f=d/16) at byte (K*32+f)*1024 + lane*16 + j*2, holding
// V[K*32 + (lane>>4)*8 + j][f*16 + (lane&15)]
__global__ __launch_bounds__(256) void k_proj(
    const f16* __restrict__ Xh, const f16* __restrict__ Wh,
    f16* __restrict__ Qh, f16* __restrict__ Kh, f16* __restrict__ VB) {
  __shared__ __align__(16) char Al[128 * 128];
  __shared__ __align__(16) char Bl[128 * 128];
  const int tid = threadIdx.x;
  const int w = tid >> 6, lane = tid & 63;
  const int m0 = blockIdx.x * 128;
  const int n0 = blockIdx.y * 128;
  const int wr = (w >> 1) * 64;
  const int wc = (w & 1) * 64;

  f32x4 acc[4][4];
#pragma unroll
  for (int i = 0; i < 4; ++i)
#pragma unroll
    for (int j = 0; j < 4; ++j) acc[i][j] = (f32x4){0.f, 0.f, 0.f, 0.f};

  const char* Xb = (const char*)Xh;
  const char* Wb = (const char*)Wh;

  for (int kb = 0; kb < DDIM; kb += 64) {
    __syncthreads();
#pragma unroll
    for (int i = 0; i < 4; ++i) {
      int ch = w * 4 + i;
      int srow = lane >> 3;
      int scol = ((lane & 7) * 16) ^ (srow << 4);
      gload_lds16(Xb + (size_t)(m0 + ch * 8 + srow) * 1024 + kb * 2 + scol, Al + ch * 1024);
      gload_lds16(Wb + (size_t)(n0 + ch * 8 + srow) * 1024 + kb * 2 + scol, Bl + ch * 1024);
    }
    __syncthreads();
#pragma unroll
    for (int ks = 0; ks < 2; ++ks) {
      f16x8 a[4], b[4];
#pragma unroll
      for (int mf = 0; mf < 4; ++mf) {
        int row = wr + mf * 16 + (lane & 15);
        int col = (ks * 64 + ((lane >> 4) * 16)) ^ ((row & 7) << 4);
        a[mf] = *(const f16x8*)(Al + row * 128 + col);
      }
#pragma unroll
      for (int nf = 0; nf < 4; ++nf) {
        int row = wc + nf * 16 + (lane & 15);
        int col = (ks * 64 + ((lane >> 4) * 16)) ^ ((row & 7) << 4);
        b[nf] = *(const f16x8*)(Bl + row * 128 + col);
      }
#pragma unroll
      for (int mf = 0; mf < 4; ++mf)
#pragma unroll
        for (int nf = 0; nf < 4; ++nf)
          acc[mf][nf] = __builtin_amdgcn_mfma_f32_16x16x32_f16(a[mf], b[nf], acc[mf][nf], 0, 0, 0);
    }
  }
  int mat = n0 >> 9;
  int nbase = n0 & 511;
  if (mat == 2) {
#pragma unroll
    for (int mf = 0; mf < 4; ++mf) {
      int R0 = m0 + wr + mf * 16 + (lane >> 4) * 4;
      int K = R0 >> 5;
      int lhi = ((R0 >> 3) & 3) * 16;
      int j0 = R0 & 7;
#pragma unroll
      for (int nf = 0; nf < 4; ++nf) {
        int col = nbase + wc + nf * 16 + (lane & 15);
        f16x4 h = {(f16)acc[mf][nf][0], (f16)acc[mf][nf][1],
                   (f16)acc[mf][nf][2], (f16)acc[mf][nf][3]};
        *(f16x4*)((char*)VB + (size_t)(K * 32 + (col >> 4)) * 1024 +
                  (lhi + (col & 15)) * 16 + j0 * 2) = h;
      }
    }
  } else {
    f16* dst = (mat == 0) ? Qh : Kh;
    float scale = (mat == 0) ? QSCALE : 1.0f;
#pragma unroll
    for (int mf = 0; mf < 4; ++mf)
#pragma unroll
      for (int nf = 0; nf < 4; ++nf)
#pragma unroll
        for (int r = 0; r < 4; ++r) {
          int row = m0 + wr + mf * 16 + (lane >> 4) * 4 + r;
          int col = nbase + wc + nf * 16 + (lane & 15);
          dst[(size_t)row * DDIM + col] = (f16)(acc[mf][nf][r] * scale);
        }
  }
}

// ---------------- causal flash attention, v5 -------------------------------
// BM=128, KVB=32, 256 blocks x 8 waves, split-KV as v2. Wave owns 16 rows x
// full 512 d. ONE barrier per iter:
//   barrier -> stage K(it+1),V(it+1) into buf^1 -> QK^T(it) from Kl[buf] ->
//   DPP softmax (in-reg stats) -> P write (wave-private LDS) -> PV(it) from
//   Vl[buf] -> vmcnt(0) [staging landed long ago] -> barrier
__global__ __launch_bounds__(512, 2) void k_flash(
    const f16* __restrict__ Qh, const f16* __restrict__ Kh,
    const f16* __restrict__ VBg, f16* __restrict__ Opart,
    float* __restrict__ Mpart, float* __restrict__ Lpart,
    int* __restrict__ TilePart) {
  __shared__ __align__(16) char Kl[2][32768];   // K tile [32][512 f16] swizzled
  __shared__ __align__(16) char Vl[2][32768];   // V frag-packed [32 frags][1KB]
  __shared__ __align__(16) char Pl[8][1024];    // per-wave P [16][32] f16 swz

  const int tid = threadIdx.x;
  const int w = tid >> 6, lane = tid & 63;
  const int l15 = lane & 15, l4 = lane >> 4;

  int bid = blockIdx.x;
  int b = (bid & 7) * 32 + (bid >> 3);          // XCD-contiguous logical id
  int g  = (GTOT * b) >> 8;
  int g1 = (GTOT * (b + 1)) >> 8;
  int t = 0;
  while (2 * (t + 1) * (t + 2) <= g) ++t;

  const char* Kb = (const char*)Kh;
  const char* Vb = (const char*)VBg;

#define STAGEKV(KB, BI) do {                                                   \
    _Pragma("unroll")                                                          \
    for (int i_ = 0; i_ < 4; ++i_) {                                           \
      int row_ = w * 4 + i_;                                                   \
      int scol_ = (lane * 16) ^ ((row_ & 7) << 4);                             \
      gload_lds16(Kb + (size_t)((KB) + row_) * 1024 + scol_, Kl[BI] + row_ * 1024); \
    }                                                                          \
    const char* vs_ = Vb + (size_t)((KB) >> 5) * 32768;                        \
    _Pragma("unroll")                                                          \
    for (int i_ = 0; i_ < 4; ++i_) {                                           \
      int ch_ = w * 4 + i_;                                                    \
      gload_lds16(vs_ + ch_ * 1024 + lane * 16, Vl[BI] + ch_ * 1024);          \
    } } while (0)

  while (g < g1) {
    int Ct  = 2 * t * (t + 1);
    int Ct1 = 2 * (t + 1) * (t + 2);
    int gend = min(g1, Ct1);
    int n = gend - g;
    int kb0 = (g - Ct) * 32;
    int q0 = t * 128;
    int slot = b + t;

    // Q fragments: rows q0 + w*16 + l15, full D
    f16x8 qf[16];
    {
      const f16* qp = Qh + (size_t)(q0 + w * 16 + l15) * DDIM + l4 * 8;
#pragma unroll
      for (int ks = 0; ks < 16; ++ks) qf[ks] = *(const f16x8*)(qp + ks * 32);
    }
    f32x4 acc[32];
#pragma unroll
    for (int i = 0; i < 32; ++i) acc[i] = (f32x4){0.f, 0.f, 0.f, 0.f};
    float mreg[4], lreg[4];
#pragma unroll
    for (int r = 0; r < 4; ++r) { mreg[r] = -3.0e38f; lreg[r] = 0.f; }

    // prologue: stage tile 0, wait, open steady state
    STAGEKV(kb0, 0);
    asm volatile("s_waitcnt vmcnt(0)" ::: "memory");
    __builtin_amdgcn_s_barrier();

    for (int it = 0; it < n; ++it) {
      int cur = it & 1;
      if (it + 1 < n) STAGEKV(kb0 + (it + 1) * 32, cur ^ 1);

      // ---- QK^T(it): S[16 x 32] per wave over d=512
      const char* KlB = Kl[cur];
      f32x4 s0 = (f32x4){0.f, 0.f, 0.f, 0.f};
      f32x4 s1 = (f32x4){0.f, 0.f, 0.f, 0.f};
      __builtin_amdgcn_s_setprio(1);
#pragma unroll
      for (int ks = 0; ks < 16; ++ks) {
        int off = ks * 64 + l4 * 16;
        f16x8 kf0 = *(const f16x8*)(KlB + l15 * 1024 + (off ^ ((l15 & 7) << 4)));
        s0 = __builtin_amdgcn_mfma_f32_16x16x32_f16(qf[ks], kf0, s0, 0, 0, 0);
        f16x8 kf1 = *(const f16x8*)(KlB + (16 + l15) * 1024 + (off ^ ((l15 & 7) << 4)));
        s1 = __builtin_amdgcn_mfma_f32_16x16x32_f16(qf[ks], kf1, s1, 0, 0, 0);
      }
      __builtin_amdgcn_s_setprio(0);

      // ---- softmax (in-reg, DPP row reductions; wave-private stats)
      {
        int kb = kb0 + it * 32;
        float p0[4], p1[4], mx[4];
        int qrb = q0 + w * 16 + l4 * 4;
        int kc = kb + l15;
#pragma unroll
        for (int r = 0; r < 4; ++r) {
          int qr = qrb + r;
          float x0 = (kc      <= qr) ? s0[r] : -3.0e38f;
          float x1 = (kc + 16 <= qr) ? s1[r] : -3.0e38f;
          p0[r] = x0; p1[r] = x1;
          mx[r] = rowmax16(fmaxf(x0, x1));
        }
        bool need = (mx[0] > mreg[0] + 8.f) || (mx[1] > mreg[1] + 8.f) ||
                    (mx[2] > mreg[2] + 8.f) || (mx[3] > mreg[3] + 8.f);
        if (__any(need)) {                       // T13 defer-rescale, THR=8
          float alpha[4];
#pragma unroll
          for (int r = 0; r < 4; ++r) {
            float mn = fmaxf(mreg[r], mx[r]);
            alpha[r] = exp2f((mreg[r] - mn) * L2E);
            lreg[r] *= alpha[r];
            mreg[r] = mn;
          }
#pragma unroll
          for (int nf = 0; nf < 32; ++nf) {
            acc[nf][0] *= alpha[0];
            acc[nf][1] *= alpha[1];
            acc[nf][2] *= alpha[2];
            acc[nf][3] *= alpha[3];
          }
        }
#pragma unroll
        for (int r = 0; r < 4; ++r) {
          int qr = qrb + r;
          float e0 = (kc      <= qr) ? exp2f((p0[r] - mreg[r]) * L2E) : 0.f;
          float e1 = (kc + 16 <= qr) ? exp2f((p1[r] - mreg[r]) * L2E) : 0.f;
          p0[r] = e0; p1[r] = e1;
          lreg[r] += rowsum16(e0 + e1);
        }
        // P write, wave-private: byte = row*64 + ((col*2) ^ sw(row))
        char* Pw = Pl[w];
#pragma unroll
        for (int r = 0; r < 4; ++r) {
          int row = l4 * 4 + r;
          int sw = (((row & 3) ^ (row >> 2)) & 3) << 4;
          *(f16*)(Pw + row * 64 + ((l15 * 2) ^ sw))        = (f16)p0[r];
          *(f16*)(Pw + row * 64 + (((16 + l15) * 2) ^ sw)) = (f16)p1[r];
        }
      }
      asm volatile("s_waitcnt lgkmcnt(0)" ::: "memory");  // P committed
      __builtin_amdgcn_sched_barrier(0);

      // ---- PV(it): O[16 x 512] += P[16 x 32] @ V[32 x 512]
      {
        const char* VlB = Vl[cur];
        char* Pw = Pl[w];
        int prow = l15;
        int sw = (((prow & 3) ^ (prow >> 2)) & 3) << 4;
        f16x8 pa = *(const f16x8*)(Pw + prow * 64 + ((l4 * 16) ^ sw));
        __builtin_amdgcn_s_setprio(1);
#pragma unroll
        for (int nf = 0; nf < 32; ++nf) {
          f16x8 vb = *(const f16x8*)(VlB + nf * 1024 + lane * 16);
          acc[nf] = __builtin_amdgcn_mfma_f32_16x16x32_f16(pa, vb, acc[nf], 0, 0, 0);
        }
        __builtin_amdgcn_s_setprio(0);
      }

      if (it + 1 < n)
        asm volatile("s_waitcnt vmcnt(0)" ::: "memory");  // staged long ago: ~free
      __builtin_amdgcn_s_barrier();
    }

    // ---- epilogue: all stats in-reg (DPP-reduced => uniform per row group)
    {
      float inv[4];
#pragma unroll
      for (int r = 0; r < 4; ++r) inv[r] = (lreg[r] > 0.f) ? 1.f / lreg[r] : 0.f;
      f16* op = Opart + (size_t)slot * (128 * 512);
      int rowb = w * 16 + l4 * 4;
#pragma unroll
      for (int nf = 0; nf < 32; ++nf) {
        int col = nf * 16 + l15;
#pragma unroll
        for (int r = 0; r < 4; ++r)
          op[(size_t)(rowb + r) * 512 + col] = (f16)(acc[nf][r] * inv[r]);
      }
      if (l15 == 0) {
#pragma unroll
        for (int r = 0; r < 4; ++r) {
          Mpart[slot * 128 + rowb + r] = mreg[r];
          Lpart[slot * 128 + rowb + r] = lreg[r];
        }
      }
      if (tid == 0) TilePart[slot] = t;
    }
    g = gend;
    ++t;
  }
#undef STAGEKV
}

// ---------------- combine partials -> out --------------------------------
__global__ __launch_bounds__(256) void k_reduce(
    const f16* __restrict__ Opart, const float* __restrict__ Mpart,
    const float* __restrict__ Lpart, const int* __restrict__ TilePart,
    float* __restrict__ out) {
  __shared__ int tp[NSLOT];
  __shared__ int sl[16];
  __shared__ int scnt;
  int tid = threadIdx.x;
  int t = blockIdx.x >> 2, rg = blockIdx.x & 3;
  for (int s = tid; s < NSLOT; s += 256) tp[s] = TilePart[s];
  __syncthreads();
  if (tid == 0) {
    int c = 0;
    for (int s = 0; s < NSLOT; ++s)
      if (tp[s] == t && c < 16) sl[c++] = s;
    scnt = c;
  }
  __syncthreads();
  int cnt = scnt;
  int rowIn = rg * 32 + (tid >> 3);
  int row = t * 128 + rowIn;
  int col0 = (tid & 7) * 64;

  float M = -3.0e38f;
  for (int i = 0; i < cnt; ++i) M = fmaxf(M, Mpart[sl[i] * 128 + rowIn]);
  float a[64];
#pragma unroll
  for (int j = 0; j < 64; ++j) a[j] = 0.f;
  float denom = 0.f;
  for (int i = 0; i < cnt; ++i) {
    int s = sl[i];
    float m = Mpart[s * 128 + rowIn];
    float l = Lpart[s * 128 + rowIn];
    float wgt = exp2f((m - M) * L2E) * l;
    denom += wgt;
    const f16* op = Opart + (size_t)s * 65536 + rowIn * 512 + col0;
#pragma unroll
    for (int v = 0; v < 8; ++v) {
      f16x8 x = *(const f16x8*)(op + v * 8);
#pragma unroll
      for (int j = 0; j < 8; ++j) a[v * 8 + j] += wgt * (float)x[j];
    }
  }
  float inv = (denom > 0.f) ? 1.f / denom : 0.f;
  float* o = out + (size_t)row * 512 + col0;
#pragma unroll
  for (int j = 0; j < 64; ++j) o[j] = a[j] * inv;
}

extern "C" void kernel_launch(void* const* d_in, const int* in_sizes, int n_in,
                              void* d_out, int out_size, void* d_ws, size_t ws_size,
                              hipStream_t stream) {
  const float* X  = (const float*)d_in[0];
  const float* Wq = (const float*)d_in[2];
  const float* Wk = (const float*)d_in[3];
  const float* Wv = (const float*)d_in[4];
  float* out = (float*)d_out;

  char* ws = (char*)d_ws;
  f16*   Opart = (f16*)(ws);                               // 40 MiB
  float* Mpart = (float*)(ws + (40u << 20));               // 160 KiB
  float* Lpart = (float*)(ws + (41u << 20));               // 160 KiB
  int*   TileP = (int*)(ws + (42u << 20));                 // 1.25 KiB
  f16* Qh = (f16*)(ws + (43u << 20));                      // 8 MiB (pre-scaled)
  f16* Kh = (f16*)(ws + (51u << 20));                      // 8 MiB
  f16* VB = (f16*)(ws + (59u << 20));                      // 8 MiB packed frags
  f16* Xh = (f16*)(ws + (67u << 20));                      // 8 MiB
  f16* Wh = (f16*)(ws + (75u << 20));                      // 1.5 MiB

  k_init<<<5, 64, 0, stream>>>(TileP);
  k_convert<<<4864, 256, 0, stream>>>(X, Wq, Wk, Wv, Xh, Wh);
  dim3 gp(64, 12);
  k_proj<<<gp, 256, 0, stream>>>(Xh, Wh, Qh, Kh, VB);
  k_flash<<<256, 512, 0, stream>>>(Qh, Kh, VB, Opart, Mpart, Lpart, TileP);
  k_reduce<<<256, 256, 0, stream>>>(Opart, Mpart, Lpart, TileP, out);
}